// Round 4
// baseline (230.057 us; speedup 1.0000x reference)
//
#include <hip/hip_runtime.h>
#include <math.h>

#define T_STEPS 32
#define B_SZ    512
#define D_SZ    1024
#define C_SZ    1000
#define KZ      8           // GEMM2 split-K factor
#define HP      132         // LDS h-tile pitch (bf16) — breaks quad bank aliasing

typedef __bf16 bf16x8 __attribute__((ext_vector_type(8)));
typedef float  f32x4  __attribute__((ext_vector_type(4)));

__device__ __forceinline__ unsigned short f2bf(float f) {
    unsigned u = __float_as_uint(f);
    unsigned r = u + 0x7FFFu + ((u >> 16) & 1u);   // RNE
    return (unsigned short)(r >> 16);
}
__device__ __forceinline__ float bf2f(unsigned short b) {
    return __uint_as_float(((unsigned)b) << 16);
}

__device__ __forceinline__ void async_copy16(const void* g, void* l) {
    __builtin_amdgcn_global_load_lds(
        (const __attribute__((address_space(1))) unsigned int*)g,
        (__attribute__((address_space(3))) unsigned int*)l,
        16, 0, 0);
}

// ---------------- fused cast (x, W1, W2 -> bf16) + zero (y accum + counters) ----
#define NX4  4194304   // x:  16M floats / 4
#define NW14  262144   // W1:  1M floats / 4
#define NW24  256000   // W2:  1.024M floats / 4
#define NZ4   128001   // zero region: y (512000 f) + ctr (4 f) in float4
#define NTOT (NX4 + NW14 + NW24 + NZ4)

__global__ __launch_bounds__(256) void cast_zero_k(
    const float* __restrict__ x,  unsigned short* __restrict__ x_bf,
    const float* __restrict__ W1, unsigned short* __restrict__ W1_bf,
    const float* __restrict__ W2, unsigned short* __restrict__ W2_bf,
    float4* __restrict__ zbase)
{
    const int idx = blockIdx.x * 256 + threadIdx.x;
    if (idx >= NTOT) return;
    if (idx >= NX4 + NW14 + NW24) {
        zbase[idx - (NX4 + NW14 + NW24)] = make_float4(0.f, 0.f, 0.f, 0.f);
        return;
    }
    const float4* s; ushort4* d; int j;
    if (idx < NX4)              { s = (const float4*)x;  d = (ushort4*)x_bf;  j = idx; }
    else if (idx < NX4 + NW14)  { s = (const float4*)W1; d = (ushort4*)W1_bf; j = idx - NX4; }
    else                        { s = (const float4*)W2; d = (ushort4*)W2_bf; j = idx - NX4 - NW14; }
    const float4 v = s[j];
    ushort4 o;
    o.x = f2bf(v.x); o.y = f2bf(v.y); o.z = f2bf(v.z); o.w = f2bf(v.w);
    d[j] = o;
}

// ---------------- fused GEMM1 + bias + LIF scan -> spike counts ----------------
// A = x_bf [T*B, D] row-major; Bm = W1_bf [D, D]; cnt [B, D] bf16.
// Block tile: M-rows = {t*512 + b0 + bb}, N-tile 128. 256 thr = 4 waves (2x2),
// 16x16x32 bf16 MFMA, global_load_lds w=16 staging, XOR chunk swizzle.
__global__ __launch_bounds__(256) void gemm1_scan_k(
    const unsigned short* __restrict__ A, const unsigned short* __restrict__ Bm,
    const float* __restrict__ bias, unsigned short* __restrict__ cnt)
{
    __shared__ __align__(16) unsigned short smem[128 * HP];  // 33792 B
    unsigned short* As = smem;
    unsigned short* Bs = smem + 4096;

    const int tid  = threadIdx.x;
    const int wave = tid >> 6;
    const int lane = tid & 63;
    const int lm   = lane & 15;
    const int quad = lane >> 4;
    const int wm   = (wave >> 1) * 64;
    const int wn   = (wave & 1) * 64;

    // XCD swizzle: blocks sharing the A-tile (same yb) land on the same XCD
    const int f  = blockIdx.x;
    const int yb = f & 127;
    const int xb = f >> 7;
    const int b0 = yb * 4;
    const int n0 = xb * 128;

    f32x4 acc[4][4];
    #pragma unroll
    for (int i = 0; i < 4; ++i)
        #pragma unroll
        for (int j = 0; j < 4; ++j)
            acc[i][j] = (f32x4){0.f, 0.f, 0.f, 0.f};

    int srowA[2], sgq[2];
    size_t arowoff[2];
    unsigned ldsoff[2];
    #pragma unroll
    for (int p = 0; p < 2; ++p) {
        const int s = p * 256 + tid;
        const int rho = s >> 2;
        srowA[p] = rho;
        sgq[p]  = (s & 3) ^ ((rho >> 1) & 3);
        arowoff[p] = (size_t)((rho >> 2) * 512 + b0 + (rho & 3)) * D_SZ;
        ldsoff[p] = (unsigned)(p * 256 + wave * 64) * 16u;
    }
    const int fq = quad ^ ((lm >> 1) & 3);

    for (int k0 = 0; k0 < D_SZ; k0 += 32) {
        #pragma unroll
        for (int p = 0; p < 2; ++p) {
            async_copy16(A + arowoff[p] + k0 + sgq[p] * 8, (char*)As + ldsoff[p]);
            async_copy16(Bm + (size_t)(n0 + srowA[p]) * D_SZ + k0 + sgq[p] * 8,
                         (char*)Bs + ldsoff[p]);
        }
        __syncthreads();

        bf16x8 af[4], bfr[4];
        #pragma unroll
        for (int i = 0; i < 4; ++i) {
            af[i]  = ((const bf16x8*)As)[(wm + i * 16 + lm) * 4 + fq];
            bfr[i] = ((const bf16x8*)Bs)[(wn + i * 16 + lm) * 4 + fq];
        }
        #pragma unroll
        for (int mi = 0; mi < 4; ++mi)
            #pragma unroll
            for (int ni = 0; ni < 4; ++ni)
                acc[mi][ni] = __builtin_amdgcn_mfma_f32_16x16x32_bf16(
                    af[mi], bfr[ni], acc[mi][ni], 0, 0, 0);
        __syncthreads();
    }

    // h-tile (+bias) -> LDS
    #pragma unroll
    for (int ni = 0; ni < 4; ++ni) {
        const int nn = wn + ni * 16 + lm;
        const float bv = bias[n0 + nn];
        #pragma unroll
        for (int mi = 0; mi < 4; ++mi) {
            const f32x4 v = acc[mi][ni];
            #pragma unroll
            for (int r = 0; r < 4; ++r)
                smem[(wm + mi * 16 + quad * 4 + r) * HP + nn] = f2bf(v[r] + bv);
        }
    }
    __syncthreads();

    // LIF scan: column (bb, c): h[t] at local row t*4+bb
    #pragma unroll
    for (int rep = 0; rep < 2; ++rep) {
        const int flat = rep * 256 + tid;
        const int bb = flat >> 7;
        const int c  = flat & 127;
        float v = 0.f, cv = 0.f;
        #pragma unroll
        for (int t = 0; t < T_STEPS; ++t) {
            const float ht = bf2f(smem[(t * 4 + bb) * HP + c]);
            v = 0.5f * (v + ht);
            const float s = (v >= 1.0f) ? 1.0f : 0.0f;
            cv += s;
            v *= (1.0f - s);
        }
        cnt[(size_t)(b0 + bb) * D_SZ + n0 + c] = f2bf(cv);
    }
}

// ---------------- fused GEMM2 (split-K, atomic accum) + log_softmax ----------------
// grid (8 n-tiles, 4 m-tiles, KZ). Each block atomicAdds its 128x128 partial
// into y[512,1000] (pre-zeroed). Last of the 64 contributors per m-tile does
// bias + 1/T scale + log_softmax for its 128 rows and writes out.
__global__ __launch_bounds__(256) void gemm2_lsm_k(
    const unsigned short* __restrict__ A,   // cnt [512,1024] bf16
    const unsigned short* __restrict__ Bm,  // W2  [1000,1024] bf16
    const float* __restrict__ b2,
    float* __restrict__ y,                  // [512,1000] fp32 accum (zeroed)
    unsigned int* __restrict__ ctr,         // [4] (zeroed)
    float* __restrict__ out)                // [512,1000]
{
    __shared__ __align__(16) unsigned short As[128 * 32];
    __shared__ __align__(16) unsigned short Bs[128 * 32];
    __shared__ int lastFlag;

    const int tid  = threadIdx.x;
    const int wave = tid >> 6;
    const int lane = tid & 63;
    const int lm   = lane & 15;
    const int quad = lane >> 4;
    const int wm   = (wave >> 1) * 64;
    const int wn   = (wave & 1) * 64;
    const int n0   = blockIdx.x * 128;
    const int m0   = blockIdx.y * 128;
    const int kz   = blockIdx.z;

    f32x4 acc[4][4];
    #pragma unroll
    for (int i = 0; i < 4; ++i)
        #pragma unroll
        for (int j = 0; j < 4; ++j)
            acc[i][j] = (f32x4){0.f, 0.f, 0.f, 0.f};

    int srow[2], sgq[2];
    unsigned ldsoff[2];
    #pragma unroll
    for (int p = 0; p < 2; ++p) {
        const int s = p * 256 + tid;
        srow[p] = s >> 2;
        sgq[p]  = (s & 3) ^ ((srow[p] >> 1) & 3);
        ldsoff[p] = (unsigned)(p * 256 + wave * 64) * 16u;
    }
    const int fq = quad ^ ((lm >> 1) & 3);

    const int kbeg = kz * (D_SZ / KZ);
    for (int k0 = kbeg; k0 < kbeg + D_SZ / KZ; k0 += 32) {
        #pragma unroll
        for (int p = 0; p < 2; ++p) {
            async_copy16(A + (size_t)(m0 + srow[p]) * D_SZ + k0 + sgq[p] * 8,
                         (char*)As + ldsoff[p]);
            int brow = n0 + srow[p];
            if (brow > C_SZ - 1) brow = C_SZ - 1;
            async_copy16(Bm + (size_t)brow * D_SZ + k0 + sgq[p] * 8,
                         (char*)Bs + ldsoff[p]);
        }
        __syncthreads();

        bf16x8 af[4], bfr[4];
        #pragma unroll
        for (int i = 0; i < 4; ++i) {
            af[i]  = ((const bf16x8*)As)[(wm + i * 16 + lm) * 4 + fq];
            bfr[i] = ((const bf16x8*)Bs)[(wn + i * 16 + lm) * 4 + fq];
        }
        #pragma unroll
        for (int mi = 0; mi < 4; ++mi)
            #pragma unroll
            for (int ni = 0; ni < 4; ++ni)
                acc[mi][ni] = __builtin_amdgcn_mfma_f32_16x16x32_bf16(
                    af[mi], bfr[ni], acc[mi][ni], 0, 0, 0);
        __syncthreads();
    }

    // scatter-accumulate partial into y (device-scope atomics, coherent at L3)
    #pragma unroll
    for (int ni = 0; ni < 4; ++ni) {
        const int nn = n0 + wn + ni * 16 + lm;
        if (nn >= C_SZ) continue;
        #pragma unroll
        for (int mi = 0; mi < 4; ++mi) {
            const f32x4 v = acc[mi][ni];
            #pragma unroll
            for (int r = 0; r < 4; ++r) {
                const int mm = m0 + wm + mi * 16 + quad * 4 + r;
                atomicAdd(&y[(size_t)mm * C_SZ + nn], v[r]);
            }
        }
    }

    // last-arriver-per-m-tile does the epilogue (threadfence reduction pattern)
    __threadfence();
    __syncthreads();
    if (tid == 0) {
        const unsigned old = atomicAdd(&ctr[blockIdx.y], 1u);
        lastFlag = (old == (8 * KZ - 1)) ? 1 : 0;
    }
    __syncthreads();
    if (!lastFlag) return;
    __threadfence();

    // stage b2 in LDS (reuse As)
    float* b2s = (float*)As;
    for (int c = tid; c < C_SZ; c += 256) b2s[c] = b2[c];
    __syncthreads();

    const float inv = 1.0f / (float)T_STEPS;
    for (int i = 0; i < 32; ++i) {          // 4 waves x 32 rows = 128 rows
        const int m = m0 + wave * 32 + i;
        float vals[16];
        float mx = -1e30f;
        #pragma unroll
        for (int s = 0; s < 16; ++s) {
            const int c = s * 64 + lane;
            float v = -1e30f;
            if (c < C_SZ)
                v = __hip_atomic_load(&y[(size_t)m * C_SZ + c],
                                      __ATOMIC_RELAXED, __HIP_MEMORY_SCOPE_AGENT)
                    * inv + b2s[c];
            vals[s] = v;
            mx = fmaxf(mx, v);
        }
        #pragma unroll
        for (int off = 32; off > 0; off >>= 1)
            mx = fmaxf(mx, __shfl_down(mx, off, 64));
        mx = __shfl(mx, 0, 64);

        float sm = 0.f;
        #pragma unroll
        for (int s = 0; s < 16; ++s) {
            const int c = s * 64 + lane;
            if (c < C_SZ) sm += __expf(vals[s] - mx);
        }
        #pragma unroll
        for (int off = 32; off > 0; off >>= 1)
            sm += __shfl_down(sm, off, 64);
        sm = __shfl(sm, 0, 64);

        const float lse = mx + logf(sm);
        #pragma unroll
        for (int s = 0; s < 16; ++s) {
            const int c = s * 64 + lane;
            if (c < C_SZ) out[(size_t)m * C_SZ + c] = vals[s] - lse;
        }
    }
}

extern "C" void kernel_launch(void* const* d_in, const int* in_sizes, int n_in,
                              void* d_out, int out_size, void* d_ws, size_t ws_size,
                              hipStream_t stream)
{
    const float* x  = (const float*)d_in[0];  // [T,B,D]
    const float* W1 = (const float*)d_in[1];  // [D,D]
    const float* b1 = (const float*)d_in[2];  // [D]
    const float* W2 = (const float*)d_in[3];  // [C,D]
    const float* b2 = (const float*)d_in[4];  // [C]
    float* out = (float*)d_out;               // [B,C]

    char* ws = (char*)d_ws;
    unsigned short* x_bf   = (unsigned short*)(ws);              // 33,554,432 B
    unsigned short* W1_bf  = (unsigned short*)(ws + 33554432);   //  2,097,152 B
    unsigned short* W2_bf  = (unsigned short*)(ws + 35651584);   //  2,048,000 B
    unsigned short* cnt_bf = (unsigned short*)(ws + 37699584);   //  1,048,576 B
    float*          y32    = (float*)(ws + 38748160);            //  2,048,000 B
    unsigned int*   ctr    = (unsigned int*)(ws + 40796160);     //         16 B
    // total 40,796,176 B < ws_size (71,303,168 B proven round 1)

    // 1) fused casts + zero(y, ctr) — zbase covers [y32, ctr] contiguously
    cast_zero_k<<<(NTOT + 255) / 256, 256, 0, stream>>>(
        x, x_bf, W1, W1_bf, W2, W2_bf, (float4*)y32);

    // 2) fused GEMM1 + bias + LIF scan -> counts (1024 blocks, XCD-swizzled)
    gemm1_scan_k<<<(B_SZ / 4) * (D_SZ / 128), 256, 0, stream>>>(
        x_bf, W1_bf, b1, cnt_bf);

    // 3) fused GEMM2 split-K atomic accum + bias + 1/T + log_softmax
    {
        dim3 grid((C_SZ + 127) / 128, B_SZ / 128, KZ);
        gemm2_lsm_k<<<grid, 256, 0, stream>>>(cnt_bf, W2_bf, b2, y32, ctr, out);
    }
}

// Round 5
// 222.760 us; speedup vs baseline: 1.0328x; 1.0328x over previous
//
#include <hip/hip_runtime.h>
#include <math.h>

#define T_STEPS 32
#define B_SZ    512
#define D_SZ    1024
#define C_SZ    1000
#define KZ      2           // GEMM2 split-K factor (exclusive partial regions)
#define HP      132         // LDS h-tile pitch (bf16) — breaks quad bank aliasing

typedef __bf16 bf16x8 __attribute__((ext_vector_type(8)));
typedef float  f32x4  __attribute__((ext_vector_type(4)));

__device__ __forceinline__ unsigned short f2bf(float f) {
    unsigned u = __float_as_uint(f);
    unsigned r = u + 0x7FFFu + ((u >> 16) & 1u);   // RNE
    return (unsigned short)(r >> 16);
}
__device__ __forceinline__ float bf2f(unsigned short b) {
    return __uint_as_float(((unsigned)b) << 16);
}

__device__ __forceinline__ void async_copy16(const void* g, void* l) {
    __builtin_amdgcn_global_load_lds(
        (const __attribute__((address_space(1))) unsigned int*)g,
        (__attribute__((address_space(3))) unsigned int*)l,
        16, 0, 0);
}

// ---------------- fused cast (x, W1, W2 -> bf16) + zero ctr ----------------
#define NX4  4194304   // x:  16M floats / 4
#define NW14  262144   // W1:  1M floats / 4
#define NW24  256000   // W2:  1.024M floats / 4
#define NTOT (NX4 + NW14 + NW24 + 1)

__global__ __launch_bounds__(256) void cast_zero_k(
    const float* __restrict__ x,  unsigned short* __restrict__ x_bf,
    const float* __restrict__ W1, unsigned short* __restrict__ W1_bf,
    const float* __restrict__ W2, unsigned short* __restrict__ W2_bf,
    float4* __restrict__ ctrz)
{
    const int idx = blockIdx.x * 256 + threadIdx.x;
    if (idx >= NTOT) return;
    if (idx == NTOT - 1) {                 // zero the 4 finisher counters
        ctrz[0] = make_float4(0.f, 0.f, 0.f, 0.f);
        return;
    }
    const float4* s; ushort4* d; int j;
    if (idx < NX4)              { s = (const float4*)x;  d = (ushort4*)x_bf;  j = idx; }
    else if (idx < NX4 + NW14)  { s = (const float4*)W1; d = (ushort4*)W1_bf; j = idx - NX4; }
    else                        { s = (const float4*)W2; d = (ushort4*)W2_bf; j = idx - NX4 - NW14; }
    const float4 v = s[j];
    ushort4 o;
    o.x = f2bf(v.x); o.y = f2bf(v.y); o.z = f2bf(v.z); o.w = f2bf(v.w);
    d[j] = o;
}

// ---------------- fused GEMM1 + bias + LIF scan -> spike counts ----------------
// A = x_bf [T*B, D]; Bm = W1_bf [D, D]; cnt [B, D] bf16.
// Block tile: M-rows {t*512 + b0 + bb} (rho = t*4+bb), N-tile 128.
// BK=64: 32 KB staging (8 16B-chunks/row, XOR-swizzled), 16 K-iterations —
// half the barriers of BK=32; LDS union with 128xHP h-tile keeps 4 blocks/CU.
__global__ __launch_bounds__(256) void gemm1_scan_k(
    const unsigned short* __restrict__ A, const unsigned short* __restrict__ Bm,
    const float* __restrict__ bias, unsigned short* __restrict__ cnt)
{
    __shared__ __align__(16) unsigned short smem[128 * HP];  // 33792 B
    unsigned short* As = smem;           // 16 KB (128 rows x 8 chunks)
    unsigned short* Bs = smem + 8192;    // 16 KB

    const int tid  = threadIdx.x;
    const int wave = tid >> 6;
    const int lane = tid & 63;
    const int lm   = lane & 15;
    const int quad = lane >> 4;
    const int wm   = (wave >> 1) * 64;
    const int wn   = (wave & 1) * 64;

    // XCD swizzle: the 8 blocks sharing an A-slab (same yb) share an XCD
    const int f  = blockIdx.x;
    const int yb = f & 127;
    const int xb = f >> 7;
    const int b0 = yb * 4;
    const int n0 = xb * 128;

    f32x4 acc[4][4];
    #pragma unroll
    for (int i = 0; i < 4; ++i)
        #pragma unroll
        for (int j = 0; j < 4; ++j)
            acc[i][j] = (f32x4){0.f, 0.f, 0.f, 0.f};

    // staging: slot s = p*256+tid; row = s>>3 (8 chunks/row); phys q = s&7;
    // global chunk gq = q ^ (row&7)
    int srow[4], sgq[4];
    size_t arowoff[4];
    unsigned ldsoff[4];
    #pragma unroll
    for (int p = 0; p < 4; ++p) {
        const int s = p * 256 + tid;
        const int rho = s >> 3;
        srow[p] = rho;
        sgq[p]  = (s & 7) ^ (rho & 7);
        arowoff[p] = (size_t)((rho >> 2) * 512 + b0 + (rho & 3)) * D_SZ;  // t*512+b
        ldsoff[p] = (unsigned)(p * 256 + wave * 64) * 16u;
    }
    const int fq0 = quad ^ (lm & 7);   // kk=0 phys chunk; kk=1 is fq0^4

    for (int k0 = 0; k0 < D_SZ; k0 += 64) {
        #pragma unroll
        for (int p = 0; p < 4; ++p) {
            async_copy16(A + arowoff[p] + k0 + sgq[p] * 8, (char*)As + ldsoff[p]);
            async_copy16(Bm + (size_t)(n0 + srow[p]) * D_SZ + k0 + sgq[p] * 8,
                         (char*)Bs + ldsoff[p]);
        }
        __syncthreads();

        #pragma unroll
        for (int kk = 0; kk < 2; ++kk) {
            const int fqk = fq0 ^ (kk * 4);
            bf16x8 af[4], bfr[4];
            #pragma unroll
            for (int i = 0; i < 4; ++i) {
                af[i]  = ((const bf16x8*)As)[(wm + i * 16 + lm) * 8 + fqk];
                bfr[i] = ((const bf16x8*)Bs)[(wn + i * 16 + lm) * 8 + fqk];
            }
            #pragma unroll
            for (int mi = 0; mi < 4; ++mi)
                #pragma unroll
                for (int ni = 0; ni < 4; ++ni)
                    acc[mi][ni] = __builtin_amdgcn_mfma_f32_16x16x32_bf16(
                        af[mi], bfr[ni], acc[mi][ni], 0, 0, 0);
        }
        __syncthreads();
    }

    // h-tile (+bias) -> LDS. local row rho = wm+mi*16+quad*4+r, col = wn+ni*16+lm
    #pragma unroll
    for (int ni = 0; ni < 4; ++ni) {
        const int nn = wn + ni * 16 + lm;
        const float bv = bias[n0 + nn];
        #pragma unroll
        for (int mi = 0; mi < 4; ++mi) {
            const f32x4 v = acc[mi][ni];
            #pragma unroll
            for (int r = 0; r < 4; ++r)
                smem[(wm + mi * 16 + quad * 4 + r) * HP + nn] = f2bf(v[r] + bv);
        }
    }
    __syncthreads();

    // LIF scan: column (bb, c): h[t] at local row t*4+bb
    #pragma unroll
    for (int rep = 0; rep < 2; ++rep) {
        const int flat = rep * 256 + tid;
        const int bb = flat >> 7;
        const int c  = flat & 127;
        float v = 0.f, cv = 0.f;
        #pragma unroll
        for (int t = 0; t < T_STEPS; ++t) {
            const float ht = bf2f(smem[(t * 4 + bb) * HP + c]);
            v = 0.5f * (v + ht);
            const float s = (v >= 1.0f) ? 1.0f : 0.0f;
            cv += s;
            v *= (1.0f - s);
        }
        cnt[(size_t)(b0 + bb) * D_SZ + n0 + c] = f2bf(cv);
    }
}

// ---------------- GEMM2 split-K (exclusive stores) + finisher log_softmax ----
// grid (8 n-tiles, 4 m-tiles, KZ). Each block writes its 128x128 partial to its
// own region (plain stores). Last of the 8*KZ contributors per m-tile sums the
// KZ partials, adds bias + 1/T, log_softmax, writes out.
__global__ __launch_bounds__(256) void gemm2_lsm_k(
    const unsigned short* __restrict__ A,   // cnt [512,1024] bf16
    const unsigned short* __restrict__ Bm,  // W2  [1000,1024] bf16
    const float* __restrict__ b2,
    float* __restrict__ partial,            // [KZ,512,1000] fp32
    unsigned int* __restrict__ ctr,         // [4] (zeroed by cast_zero_k)
    float* __restrict__ out)                // [512,1000]
{
    __shared__ __align__(16) unsigned short As[128 * 32];
    __shared__ __align__(16) unsigned short Bs[128 * 32];
    __shared__ int lastFlag;

    const int tid  = threadIdx.x;
    const int wave = tid >> 6;
    const int lane = tid & 63;
    const int lm   = lane & 15;
    const int quad = lane >> 4;
    const int wm   = (wave >> 1) * 64;
    const int wn   = (wave & 1) * 64;
    const int n0   = blockIdx.x * 128;
    const int m0   = blockIdx.y * 128;
    const int kz   = blockIdx.z;

    f32x4 acc[4][4];
    #pragma unroll
    for (int i = 0; i < 4; ++i)
        #pragma unroll
        for (int j = 0; j < 4; ++j)
            acc[i][j] = (f32x4){0.f, 0.f, 0.f, 0.f};

    int srow[2], sgq[2];
    unsigned ldsoff[2];
    #pragma unroll
    for (int p = 0; p < 2; ++p) {
        const int s = p * 256 + tid;
        srow[p] = s >> 2;
        sgq[p]  = (s & 3) ^ ((srow[p] >> 1) & 3);
        ldsoff[p] = (unsigned)(p * 256 + wave * 64) * 16u;
    }
    const int fq = quad ^ ((lm >> 1) & 3);

    const int kbeg = kz * (D_SZ / KZ);
    for (int k0 = kbeg; k0 < kbeg + D_SZ / KZ; k0 += 32) {
        #pragma unroll
        for (int p = 0; p < 2; ++p) {
            async_copy16(A + (size_t)(m0 + srow[p]) * D_SZ + k0 + sgq[p] * 8,
                         (char*)As + ldsoff[p]);
            int brow = n0 + srow[p];
            if (brow > C_SZ - 1) brow = C_SZ - 1;
            async_copy16(Bm + (size_t)brow * D_SZ + k0 + sgq[p] * 8,
                         (char*)Bs + ldsoff[p]);
        }
        __syncthreads();

        bf16x8 af[4], bfr[4];
        #pragma unroll
        for (int i = 0; i < 4; ++i) {
            af[i]  = ((const bf16x8*)As)[(wm + i * 16 + lm) * 4 + fq];
            bfr[i] = ((const bf16x8*)Bs)[(wn + i * 16 + lm) * 4 + fq];
        }
        #pragma unroll
        for (int mi = 0; mi < 4; ++mi)
            #pragma unroll
            for (int ni = 0; ni < 4; ++ni)
                acc[mi][ni] = __builtin_amdgcn_mfma_f32_16x16x32_bf16(
                    af[mi], bfr[ni], acc[mi][ni], 0, 0, 0);
        __syncthreads();
    }

    // exclusive partial stores (no atomics)
    #pragma unroll
    for (int ni = 0; ni < 4; ++ni) {
        const int nn = n0 + wn + ni * 16 + lm;
        if (nn >= C_SZ) continue;
        #pragma unroll
        for (int mi = 0; mi < 4; ++mi) {
            const f32x4 v = acc[mi][ni];
            #pragma unroll
            for (int r = 0; r < 4; ++r) {
                const int mm = m0 + wm + mi * 16 + quad * 4 + r;
                partial[((size_t)kz * B_SZ + mm) * C_SZ + nn] = v[r];
            }
        }
    }

    // last-arriver-per-m-tile epilogue (fence + counter, round-4-proven)
    __threadfence();
    __syncthreads();
    if (tid == 0) {
        const unsigned old = atomicAdd(&ctr[blockIdx.y], 1u);
        lastFlag = (old == (8 * KZ - 1)) ? 1 : 0;
    }
    __syncthreads();
    if (!lastFlag) return;
    __threadfence();

    float* b2s = (float*)As;
    for (int c = tid; c < C_SZ; c += 256) b2s[c] = b2[c];
    __syncthreads();

    const float inv = 1.0f / (float)T_STEPS;
    for (int i = 0; i < 32; ++i) {          // 4 waves x 32 rows = 128 rows
        const int m = m0 + wave * 32 + i;
        float vals[16];
        float mx = -1e30f;
        #pragma unroll
        for (int s = 0; s < 16; ++s) {
            const int c = s * 64 + lane;
            float v = -1e30f;
            if (c < C_SZ) {
                float p0 = __hip_atomic_load(&partial[(size_t)m * C_SZ + c],
                                             __ATOMIC_RELAXED, __HIP_MEMORY_SCOPE_AGENT);
                float p1 = __hip_atomic_load(&partial[((size_t)B_SZ + m) * C_SZ + c],
                                             __ATOMIC_RELAXED, __HIP_MEMORY_SCOPE_AGENT);
                v = (p0 + p1) * inv + b2s[c];
            }
            vals[s] = v;
            mx = fmaxf(mx, v);
        }
        #pragma unroll
        for (int off = 32; off > 0; off >>= 1)
            mx = fmaxf(mx, __shfl_down(mx, off, 64));
        mx = __shfl(mx, 0, 64);

        float sm = 0.f;
        #pragma unroll
        for (int s = 0; s < 16; ++s) {
            const int c = s * 64 + lane;
            if (c < C_SZ) sm += __expf(vals[s] - mx);
        }
        #pragma unroll
        for (int off = 32; off > 0; off >>= 1)
            sm += __shfl_down(sm, off, 64);
        sm = __shfl(sm, 0, 64);

        const float lse = mx + logf(sm);
        #pragma unroll
        for (int s = 0; s < 16; ++s) {
            const int c = s * 64 + lane;
            if (c < C_SZ) out[(size_t)m * C_SZ + c] = vals[s] - lse;
        }
    }
}

extern "C" void kernel_launch(void* const* d_in, const int* in_sizes, int n_in,
                              void* d_out, int out_size, void* d_ws, size_t ws_size,
                              hipStream_t stream)
{
    const float* x  = (const float*)d_in[0];  // [T,B,D]
    const float* W1 = (const float*)d_in[1];  // [D,D]
    const float* b1 = (const float*)d_in[2];  // [D]
    const float* W2 = (const float*)d_in[3];  // [C,D]
    const float* b2 = (const float*)d_in[4];  // [C]
    float* out = (float*)d_out;               // [B,C]

    char* ws = (char*)d_ws;
    unsigned short* x_bf    = (unsigned short*)(ws);              // 33,554,432 B
    unsigned short* W1_bf   = (unsigned short*)(ws + 33554432);   //  2,097,152 B
    unsigned short* W2_bf   = (unsigned short*)(ws + 35651584);   //  2,048,000 B
    unsigned short* cnt_bf  = (unsigned short*)(ws + 37699584);   //  1,048,576 B
    float*          partial = (float*)(ws + 38748160);            //  4,096,000 B (KZ=2)
    unsigned int*   ctr     = (unsigned int*)(ws + 42844160);     //         16 B
    // total 42,844,176 B < ws_size (71,303,168 B proven round 1)

    // 1) casts + ctr zero
    cast_zero_k<<<(NTOT + 255) / 256, 256, 0, stream>>>(
        x, x_bf, W1, W1_bf, W2, W2_bf, (float4*)ctr);

    // 2) fused GEMM1 (BK=64) + bias + LIF scan -> counts (1024 blocks)
    gemm1_scan_k<<<(B_SZ / 4) * (D_SZ / 128), 256, 0, stream>>>(
        x_bf, W1_bf, b1, cnt_bf);

    // 3) GEMM2 split-K exclusive partials + finisher (bias + 1/T + log_softmax)
    {
        dim3 grid((C_SZ + 127) / 128, B_SZ / 128, KZ);
        gemm2_lsm_k<<<grid, 256, 0, stream>>>(cnt_bf, W2_bf, b2, partial, ctr, out);
    }
}

// Round 6
// 164.459 us; speedup vs baseline: 1.3989x; 1.3545x over previous
//
#include <hip/hip_runtime.h>
#include <math.h>

#define T_STEPS 32
#define B_SZ    512
#define D_SZ    1024
#define C_SZ    1000
#define KZ      8           // GEMM2 split-K factor (exclusive partial regions)
#define HP      132         // LDS h-tile pitch (bf16) — breaks quad bank aliasing

typedef __bf16 bf16x8 __attribute__((ext_vector_type(8)));
typedef float  f32x4  __attribute__((ext_vector_type(4)));

__device__ __forceinline__ unsigned short f2bf(float f) {
    unsigned u = __float_as_uint(f);
    unsigned r = u + 0x7FFFu + ((u >> 16) & 1u);   // RNE
    return (unsigned short)(r >> 16);
}
__device__ __forceinline__ float bf2f(unsigned short b) {
    return __uint_as_float(((unsigned)b) << 16);
}

__device__ __forceinline__ void async_copy16(const void* g, void* l) {
    __builtin_amdgcn_global_load_lds(
        (const __attribute__((address_space(1))) unsigned int*)g,
        (__attribute__((address_space(3))) unsigned int*)l,
        16, 0, 0);
}

// ---------------- fused cast (x, W1, W2 -> bf16) ----------------
#define NX4  4194304   // x:  16M floats / 4
#define NW14  262144   // W1:  1M floats / 4
#define NW24  256000   // W2:  1.024M floats / 4
#define NTOT (NX4 + NW14 + NW24)

__global__ __launch_bounds__(256) void cast_k(
    const float* __restrict__ x,  unsigned short* __restrict__ x_bf,
    const float* __restrict__ W1, unsigned short* __restrict__ W1_bf,
    const float* __restrict__ W2, unsigned short* __restrict__ W2_bf)
{
    const int idx = blockIdx.x * 256 + threadIdx.x;
    if (idx >= NTOT) return;
    const float4* s; ushort4* d; int j;
    if (idx < NX4)              { s = (const float4*)x;  d = (ushort4*)x_bf;  j = idx; }
    else if (idx < NX4 + NW14)  { s = (const float4*)W1; d = (ushort4*)W1_bf; j = idx - NX4; }
    else                        { s = (const float4*)W2; d = (ushort4*)W2_bf; j = idx - NX4 - NW14; }
    const float4 v = s[j];
    ushort4 o;
    o.x = f2bf(v.x); o.y = f2bf(v.y); o.z = f2bf(v.z); o.w = f2bf(v.w);
    d[j] = o;
}

// ---------------- fused GEMM1 + bias + LIF scan -> spike counts ----------------
// A = x_bf [T*B, D]; Bm = W1_bf [D, D]; cnt [B, D] bf16.
// Block tile: M-rows {t*512 + b0 + bb} (rho = t*4+bb), N-tile 128.
// BK=64: 32 KB staging (8 16B-chunks/row, XOR-swizzled), 16 K-iterations.
__global__ __launch_bounds__(256) void gemm1_scan_k(
    const unsigned short* __restrict__ A, const unsigned short* __restrict__ Bm,
    const float* __restrict__ bias, unsigned short* __restrict__ cnt)
{
    __shared__ __align__(16) unsigned short smem[128 * HP];  // 33792 B
    unsigned short* As = smem;           // 16 KB (128 rows x 8 chunks)
    unsigned short* Bs = smem + 8192;    // 16 KB

    const int tid  = threadIdx.x;
    const int wave = tid >> 6;
    const int lane = tid & 63;
    const int lm   = lane & 15;
    const int quad = lane >> 4;
    const int wm   = (wave >> 1) * 64;
    const int wn   = (wave & 1) * 64;

    // XCD swizzle: the 8 blocks sharing an A-slab (same yb) share an XCD
    const int f  = blockIdx.x;
    const int yb = f & 127;
    const int xb = f >> 7;
    const int b0 = yb * 4;
    const int n0 = xb * 128;

    f32x4 acc[4][4];
    #pragma unroll
    for (int i = 0; i < 4; ++i)
        #pragma unroll
        for (int j = 0; j < 4; ++j)
            acc[i][j] = (f32x4){0.f, 0.f, 0.f, 0.f};

    int srow[4], sgq[4];
    size_t arowoff[4];
    unsigned ldsoff[4];
    #pragma unroll
    for (int p = 0; p < 4; ++p) {
        const int s = p * 256 + tid;
        const int rho = s >> 3;
        srow[p] = rho;
        sgq[p]  = (s & 7) ^ (rho & 7);
        arowoff[p] = (size_t)((rho >> 2) * 512 + b0 + (rho & 3)) * D_SZ;  // t*512+b
        ldsoff[p] = (unsigned)(p * 256 + wave * 64) * 16u;
    }
    const int fq0 = quad ^ (lm & 7);   // kk=0 phys chunk; kk=1 is fq0^4

    for (int k0 = 0; k0 < D_SZ; k0 += 64) {
        #pragma unroll
        for (int p = 0; p < 4; ++p) {
            async_copy16(A + arowoff[p] + k0 + sgq[p] * 8, (char*)As + ldsoff[p]);
            async_copy16(Bm + (size_t)(n0 + srow[p]) * D_SZ + k0 + sgq[p] * 8,
                         (char*)Bs + ldsoff[p]);
        }
        __syncthreads();

        #pragma unroll
        for (int kk = 0; kk < 2; ++kk) {
            const int fqk = fq0 ^ (kk * 4);
            bf16x8 af[4], bfr[4];
            #pragma unroll
            for (int i = 0; i < 4; ++i) {
                af[i]  = ((const bf16x8*)As)[(wm + i * 16 + lm) * 8 + fqk];
                bfr[i] = ((const bf16x8*)Bs)[(wn + i * 16 + lm) * 8 + fqk];
            }
            #pragma unroll
            for (int mi = 0; mi < 4; ++mi)
                #pragma unroll
                for (int ni = 0; ni < 4; ++ni)
                    acc[mi][ni] = __builtin_amdgcn_mfma_f32_16x16x32_bf16(
                        af[mi], bfr[ni], acc[mi][ni], 0, 0, 0);
        }
        __syncthreads();
    }

    // h-tile (+bias) -> LDS. local row rho = wm+mi*16+quad*4+r, col = wn+ni*16+lm
    #pragma unroll
    for (int ni = 0; ni < 4; ++ni) {
        const int nn = wn + ni * 16 + lm;
        const float bv = bias[n0 + nn];
        #pragma unroll
        for (int mi = 0; mi < 4; ++mi) {
            const f32x4 v = acc[mi][ni];
            #pragma unroll
            for (int r = 0; r < 4; ++r)
                smem[(wm + mi * 16 + quad * 4 + r) * HP + nn] = f2bf(v[r] + bv);
        }
    }
    __syncthreads();

    // LIF scan: column (bb, c): h[t] at local row t*4+bb
    #pragma unroll
    for (int rep = 0; rep < 2; ++rep) {
        const int flat = rep * 256 + tid;
        const int bb = flat >> 7;
        const int c  = flat & 127;
        float v = 0.f, cv = 0.f;
        #pragma unroll
        for (int t = 0; t < T_STEPS; ++t) {
            const float ht = bf2f(smem[(t * 4 + bb) * HP + c]);
            v = 0.5f * (v + ht);
            const float s = (v >= 1.0f) ? 1.0f : 0.0f;
            cv += s;
            v *= (1.0f - s);
        }
        cnt[(size_t)(b0 + bb) * D_SZ + n0 + c] = f2bf(cv);
    }
}

// ---------------- GEMM2 split-K: partial[z][m][n] = cnt @ W2^T (K-slice) ------
__global__ __launch_bounds__(256) void gemm2_splitk_k(
    const unsigned short* __restrict__ A, const unsigned short* __restrict__ Bm,
    float* __restrict__ partial)
{
    __shared__ __align__(16) unsigned short As[128 * 32];
    __shared__ __align__(16) unsigned short Bs[128 * 32];

    const int tid  = threadIdx.x;
    const int wave = tid >> 6;
    const int lane = tid & 63;
    const int lm   = lane & 15;
    const int quad = lane >> 4;
    const int wm   = (wave >> 1) * 64;
    const int wn   = (wave & 1) * 64;
    const int n0   = blockIdx.x * 128;
    const int m0   = blockIdx.y * 128;
    const int kz   = blockIdx.z;

    f32x4 acc[4][4];
    #pragma unroll
    for (int i = 0; i < 4; ++i)
        #pragma unroll
        for (int j = 0; j < 4; ++j)
            acc[i][j] = (f32x4){0.f, 0.f, 0.f, 0.f};

    int srow[2], sgq[2];
    unsigned ldsoff[2];
    #pragma unroll
    for (int p = 0; p < 2; ++p) {
        const int s = p * 256 + tid;
        srow[p] = s >> 2;
        sgq[p]  = (s & 3) ^ ((srow[p] >> 1) & 3);
        ldsoff[p] = (unsigned)(p * 256 + wave * 64) * 16u;
    }
    const int fq = quad ^ ((lm >> 1) & 3);

    const int kbeg = kz * (D_SZ / KZ);
    for (int k0 = kbeg; k0 < kbeg + D_SZ / KZ; k0 += 32) {
        #pragma unroll
        for (int p = 0; p < 2; ++p) {
            async_copy16(A + (size_t)(m0 + srow[p]) * D_SZ + k0 + sgq[p] * 8,
                         (char*)As + ldsoff[p]);
            int brow = n0 + srow[p];
            if (brow > C_SZ - 1) brow = C_SZ - 1;
            async_copy16(Bm + (size_t)brow * D_SZ + k0 + sgq[p] * 8,
                         (char*)Bs + ldsoff[p]);
        }
        __syncthreads();

        bf16x8 af[4], bfr[4];
        #pragma unroll
        for (int i = 0; i < 4; ++i) {
            af[i]  = ((const bf16x8*)As)[(wm + i * 16 + lm) * 4 + fq];
            bfr[i] = ((const bf16x8*)Bs)[(wn + i * 16 + lm) * 4 + fq];
        }
        #pragma unroll
        for (int mi = 0; mi < 4; ++mi)
            #pragma unroll
            for (int ni = 0; ni < 4; ++ni)
                acc[mi][ni] = __builtin_amdgcn_mfma_f32_16x16x32_bf16(
                    af[mi], bfr[ni], acc[mi][ni], 0, 0, 0);
        __syncthreads();
    }

    #pragma unroll
    for (int ni = 0; ni < 4; ++ni) {
        const int nn = n0 + wn + ni * 16 + lm;
        if (nn >= C_SZ) continue;
        #pragma unroll
        for (int mi = 0; mi < 4; ++mi) {
            const f32x4 v = acc[mi][ni];
            #pragma unroll
            for (int r = 0; r < 4; ++r) {
                const int mm = m0 + wm + mi * 16 + quad * 4 + r;
                partial[((size_t)kz * B_SZ + mm) * C_SZ + nn] = v[r];
            }
        }
    }
}

// ---------------- reduce partials + bias + log_softmax ----------------
__global__ __launch_bounds__(256) void reduce_lsm_k(
    const float* __restrict__ partial, const float* __restrict__ b2,
    float* __restrict__ out)
{
    __shared__ float red_max[4];
    __shared__ float red_sum[4];

    const int b   = blockIdx.x;
    const int tid = threadIdx.x;

    float vals[4];
    float m = -1e30f;
    #pragma unroll
    for (int k = 0; k < 4; ++k) {
        const int c = tid + k * 256;
        if (c < C_SZ) {
            float s = 0.f;
            #pragma unroll
            for (int z = 0; z < KZ; ++z)
                s += partial[((size_t)z * B_SZ + b) * C_SZ + c];
            vals[k] = s * (1.0f / (float)T_STEPS) + b2[c];
        } else {
            vals[k] = -1e30f;
        }
        m = fmaxf(m, vals[k]);
    }
    #pragma unroll
    for (int off = 32; off > 0; off >>= 1)
        m = fmaxf(m, __shfl_down(m, off, 64));
    const int wave = tid >> 6;
    const int lane = tid & 63;
    if (lane == 0) red_max[wave] = m;
    __syncthreads();
    m = fmaxf(fmaxf(red_max[0], red_max[1]), fmaxf(red_max[2], red_max[3]));

    float s = 0.f;
    #pragma unroll
    for (int k = 0; k < 4; ++k) {
        const int c = tid + k * 256;
        if (c < C_SZ) s += __expf(vals[k] - m);
    }
    #pragma unroll
    for (int off = 32; off > 0; off >>= 1)
        s += __shfl_down(s, off, 64);
    if (lane == 0) red_sum[wave] = s;
    __syncthreads();
    s = red_sum[0] + red_sum[1] + red_sum[2] + red_sum[3];

    const float lse = m + logf(s);
    #pragma unroll
    for (int k = 0; k < 4; ++k) {
        const int c = tid + k * 256;
        if (c < C_SZ) out[(size_t)b * C_SZ + c] = vals[k] - lse;
    }
}

extern "C" void kernel_launch(void* const* d_in, const int* in_sizes, int n_in,
                              void* d_out, int out_size, void* d_ws, size_t ws_size,
                              hipStream_t stream)
{
    const float* x  = (const float*)d_in[0];  // [T,B,D]
    const float* W1 = (const float*)d_in[1];  // [D,D]
    const float* b1 = (const float*)d_in[2];  // [D]
    const float* W2 = (const float*)d_in[3];  // [C,D]
    const float* b2 = (const float*)d_in[4];  // [C]
    float* out = (float*)d_out;               // [B,C]

    char* ws = (char*)d_ws;
    unsigned short* x_bf    = (unsigned short*)(ws);              // 33,554,432 B
    unsigned short* W1_bf   = (unsigned short*)(ws + 33554432);   //  2,097,152 B
    unsigned short* W2_bf   = (unsigned short*)(ws + 35651584);   //  2,048,000 B
    unsigned short* cnt_bf  = (unsigned short*)(ws + 37699584);   //  1,048,576 B
    float*          partial = (float*)(ws + 38748160);            // 16,384,000 B (KZ=8)
    // total 55,132,160 B < ws_size (71,303,168 B proven round 1)

    // 1) casts
    cast_k<<<(NTOT + 255) / 256, 256, 0, stream>>>(
        x, x_bf, W1, W1_bf, W2, W2_bf);

    // 2) fused GEMM1 (BK=64) + bias + LIF scan -> counts (1024 blocks)
    gemm1_scan_k<<<(B_SZ / 4) * (D_SZ / 128), 256, 0, stream>>>(
        x_bf, W1_bf, b1, cnt_bf);

    // 3) GEMM2 split-K exclusive partials
    {
        dim3 grid((C_SZ + 127) / 128, B_SZ / 128, KZ);
        gemm2_splitk_k<<<grid, 256, 0, stream>>>(cnt_bf, W2_bf, partial);
    }

    // 4) reduce + bias + 1/T + log_softmax
    reduce_lsm_k<<<B_SZ, 256, 0, stream>>>(partial, b2, out);
}